// Round 5
// baseline (577.625 us; speedup 1.0000x reference)
//
#include <hip/hip_runtime.h>
#include <math.h>

#define D_MODEL 2048
#define NH 16
#define Q_LORA 1536
#define KV_LORA 512
#define DN 128
#define DR 64
#define DV 128
#define BB 2
#define SS 2048
#define NROWS (BB*SS)
#define LN_EPS 1e-5f
#define FSCALE 0.07216878364870322f   // 1/sqrt(192)

typedef __attribute__((ext_vector_type(8))) short short8;
typedef __attribute__((ext_vector_type(4))) float f32x4;

__device__ __forceinline__ ushort f2bf(float f) {
    unsigned int u = __float_as_uint(f);
    u = u + 0x7fffu + ((u >> 16) & 1u);   // round-to-nearest-even
    return (ushort)(u >> 16);
}

// ---------------------------------------------------------------------------
// Trig table: cos/sin[s][i] for s in [0,2048), i in [0,32).
// ---------------------------------------------------------------------------
__global__ __launch_bounds__(256)
void build_trig(const int* __restrict__ pos, float* __restrict__ cosT,
                float* __restrict__ sinT)
{
    int idx = blockIdx.x * 256 + threadIdx.x;   // 65536
    int s = idx >> 5, i = idx & 31;
    double ang = (double)pos[s] * exp(-(double)i * 0.28782313662425572); // ln(1e4)/32
    cosT[idx] = (float)cos(ang);
    sinT[idx] = (float)sin(ang);
}

// ---------------------------------------------------------------------------
// Fused fp32 -> bf16 converter: hs, w_qa, w_qb, w_qrope, w_kvb, w_o + padded w_kva.
// ---------------------------------------------------------------------------
__device__ __forceinline__ void cv4(const float* __restrict__ s,
                                    ushort* __restrict__ d, long i) {
    float4 v = ((const float4*)s)[i];
    ushort4 o;
    o.x = f2bf(v.x); o.y = f2bf(v.y); o.z = f2bf(v.z); o.w = f2bf(v.w);
    ((ushort4*)d)[i] = o;
}

__global__ __launch_bounds__(256)
void cvt_all(const float* __restrict__ hs,     const float* __restrict__ w_qa,
             const float* __restrict__ w_qb,   const float* __restrict__ w_qrope,
             const float* __restrict__ w_kvb,  const float* __restrict__ w_o,
             const float* __restrict__ w_kva,
             ushort* __restrict__ hs_bf,       ushort* __restrict__ w_qa_bf,
             ushort* __restrict__ w_qb_bf,     ushort* __restrict__ w_qrope_bf,
             ushort* __restrict__ w_kvb_bf,    ushort* __restrict__ w_o_bf,
             ushort* __restrict__ w_kva_bf)
{
    long i = (long)blockIdx.x * 256 + threadIdx.x;
    if (i < 2097152) { cv4(hs, hs_bf, i); return; }
    i -= 2097152;
    if (i < 786432) { cv4(w_qa, w_qa_bf, i); return; }
    i -= 786432;
    if (i < 786432) { cv4(w_qb, w_qb_bf, i); return; }
    i -= 786432;
    if (i < 393216) { cv4(w_qrope, w_qrope_bf, i); return; }
    i -= 393216;
    if (i < 524288) { cv4(w_kvb, w_kvb_bf, i); return; }
    i -= 524288;
    if (i < 1048576) { cv4(w_o, w_o_bf, i); return; }
    i -= 1048576;
    if (i >= 327680) return;
    // w_kva: 576x2048 -> padded 640x2048 (zero fill)
    long e = i * 4;
    int row = (int)(e >> 11), col = (int)(e & 2047);
    ushort4 o;
    if (row < 576) {
        float4 v = *(const float4*)(w_kva + (long)row * 2048 + col);
        o.x = f2bf(v.x); o.y = f2bf(v.y); o.z = f2bf(v.z); o.w = f2bf(v.w);
    } else { o.x = 0; o.y = 0; o.z = 0; o.w = 0; }
    *(ushort4*)(w_kva_bf + (long)row * 2048 + col) = o;
}

// ---------------------------------------------------------------------------
// Shared bf16 MFMA GEMM core: C128x128 = A @ B^T tile, BK=32, 256 thr, GLL16.
// ---------------------------------------------------------------------------
#define GLL16(g, l) \
    __builtin_amdgcn_global_load_lds((const __attribute__((address_space(1))) void*)(g), \
                                     (__attribute__((address_space(3))) void*)(l), 16, 0, 0)

__device__ __forceinline__ void gemm_core(const ushort* __restrict__ A,
    const ushort* __restrict__ Bp, ushort* As, ushort* Bs,
    int K, int lda, int ldb, int m0, int n0, int tid, f32x4 acc[4][4])
{
    int l = tid & 63, w = tid >> 6;
    int l15 = l & 15, quad = l >> 4;
    int wm = (w >> 1) * 64, wn = (w & 1) * 64;
    int ob = tid * 16;
    int row = ob >> 6, colb = ob & 63;
    const char* ga0 = (const char*)(A  + (long)(m0 + row) * lda)      + colb;
    const char* ga1 = (const char*)(A  + (long)(m0 + row + 64) * lda) + colb;
    const char* gb0 = (const char*)(Bp + (long)(n0 + row) * ldb)      + colb;
    const char* gb1 = (const char*)(Bp + (long)(n0 + row + 64) * ldb) + colb;
    ushort* la0 = As + tid * 8;
    ushort* la1 = As + 2048 + tid * 8;
    ushort* lb0 = Bs + tid * 8;
    ushort* lb1 = Bs + 2048 + tid * 8;

    for (int k0 = 0; k0 < K; k0 += 32) {
        GLL16(ga0, la0); GLL16(ga1, la1);
        GLL16(gb0, lb0); GLL16(gb1, lb1);
        ga0 += 64; ga1 += 64; gb0 += 64; gb1 += 64;
        __syncthreads();
        short8 af[4], bf[4];
        #pragma unroll
        for (int i = 0; i < 4; ++i)
            af[i] = *(const short8*)(As + (wm + i * 16 + l15) * 32 + quad * 8);
        #pragma unroll
        for (int j = 0; j < 4; ++j)
            bf[j] = *(const short8*)(Bs + (wn + j * 16 + l15) * 32 + quad * 8);
        #pragma unroll
        for (int i = 0; i < 4; ++i)
            #pragma unroll
            for (int j = 0; j < 4; ++j)
                acc[i][j] = __builtin_amdgcn_mfma_f32_16x16x32_bf16(
                    af[i], bf[j], acc[i][j], 0, 0, 0);
        __syncthreads();
    }
}

// ---------------------------------------------------------------------------
// Mega GEMM 1: hs @ [w_qa; w_kva]^T.  N-regions:
//   n0 <  1536 : q_mixed -> q_lat_f fp32 (ldc 1536)
//   n0 <  2048 : kv cols [n0-1536, +128) -> kv_mix fp32 (ldc 512)
//   n0 == 2048 : kv cols 512..576 -> RoPE -> k_rope bf16 [4096][64]
// ---------------------------------------------------------------------------
__global__ __launch_bounds__(256)
void gemm_mega1(const ushort* __restrict__ A, const ushort* __restrict__ B,
                float* __restrict__ qlat, float* __restrict__ kvmix,
                ushort* __restrict__ krope,
                const float* __restrict__ cosT, const float* __restrict__ sinT)
{
    __shared__ __align__(16) ushort As[128 * 32];
    __shared__ __align__(16) ushort Bs[128 * 32];
    int tid = threadIdx.x;
    int m0 = blockIdx.y * 128, n0 = blockIdx.x * 128;
    f32x4 acc[4][4] = {};
    gemm_core(A, B, As, Bs, D_MODEL, D_MODEL, D_MODEL, m0, n0, tid, acc);
    int l = tid & 63, w = tid >> 6;
    int l15 = l & 15, quad = l >> 4;
    int wm = (w >> 1) * 64, wn = (w & 1) * 64;
    if (n0 < 1536) {
        #pragma unroll
        for (int i = 0; i < 4; ++i)
            #pragma unroll
            for (int j = 0; j < 4; ++j)
                #pragma unroll
                for (int r = 0; r < 4; ++r) {
                    long gm = m0 + wm + i * 16 + quad * 4 + r;
                    qlat[gm * Q_LORA + n0 + wn + j * 16 + l15] = acc[i][j][r];
                }
    } else if (n0 < 2048) {
        int c0 = n0 - 1536;
        #pragma unroll
        for (int i = 0; i < 4; ++i)
            #pragma unroll
            for (int j = 0; j < 4; ++j)
                #pragma unroll
                for (int r = 0; r < 4; ++r) {
                    long gm = m0 + wm + i * 16 + quad * 4 + r;
                    kvmix[gm * KV_LORA + c0 + wn + j * 16 + l15] = acc[i][j][r];
                }
    } else {
        if (wn != 0) return;                  // cols 64..127 are zero pad
        #pragma unroll
        for (int i = 0; i < 4; ++i)
            #pragma unroll
            for (int r = 0; r < 4; ++r) {
                long gm = m0 + wm + i * 16 + quad * 4 + r;
                int s = (int)(gm & (SS - 1));
                #pragma unroll
                for (int j = 0; j < 2; ++j) {
                    int irot = j * 16 + l15;  // [0,32)
                    float c  = cosT[s * 32 + irot];
                    float sn = sinT[s * 32 + irot];
                    float x1 = acc[i][j][r], x2 = acc[i][j + 2][r];
                    krope[gm * 64 + irot]      = f2bf(x1 * c - x2 * sn);
                    krope[gm * 64 + irot + 32] = f2bf(x1 * sn + x2 * c);
                }
            }
    }
}

// ---------------------------------------------------------------------------
// q23: q_lat_bf @ [w_qb; w_qrope]^T (rows adjacent). N-regions:
//   n0 < 2048 : q_nope -> q_full[:, h, 0:128] bf16 (x FSCALE)
//   else      : q_rope -> RoPE -> q_full[:, h, 128:192] bf16 (x FSCALE)
// ---------------------------------------------------------------------------
__global__ __launch_bounds__(256)
void gemm_q23(const ushort* __restrict__ A, const ushort* __restrict__ B,
              ushort* __restrict__ qfull,
              const float* __restrict__ cosT, const float* __restrict__ sinT)
{
    __shared__ __align__(16) ushort As[128 * 32];
    __shared__ __align__(16) ushort Bs[128 * 32];
    int tid = threadIdx.x;
    int m0 = blockIdx.y * 128, n0 = blockIdx.x * 128;
    f32x4 acc[4][4] = {};
    gemm_core(A, B, As, Bs, Q_LORA, Q_LORA, Q_LORA, m0, n0, tid, acc);
    int l = tid & 63, w = tid >> 6;
    int l15 = l & 15, quad = l >> 4;
    int wm = (w >> 1) * 64, wn = (w & 1) * 64;
    if (n0 < 2048) {
        int head = n0 >> 7;
        #pragma unroll
        for (int i = 0; i < 4; ++i)
            #pragma unroll
            for (int j = 0; j < 4; ++j)
                #pragma unroll
                for (int r = 0; r < 4; ++r) {
                    long gm = m0 + wm + i * 16 + quad * 4 + r;
                    int c = wn + j * 16 + l15;
                    qfull[(gm * NH + head) * 192 + c] = f2bf(acc[i][j][r] * FSCALE);
                }
    } else {
        int head = ((n0 - 2048) + wn) >> 6;
        #pragma unroll
        for (int i = 0; i < 4; ++i)
            #pragma unroll
            for (int r = 0; r < 4; ++r) {
                long gm = m0 + wm + i * 16 + quad * 4 + r;
                int s = (int)(gm & (SS - 1));
                ushort* op = qfull + (gm * NH + head) * 192 + 128;
                #pragma unroll
                for (int j = 0; j < 2; ++j) {
                    int irot = j * 16 + l15;  // [0,32)
                    float c  = cosT[s * 32 + irot];
                    float sn = sinT[s * 32 + irot];
                    float x1 = acc[i][j][r], x2 = acc[i][j + 2][r];
                    op[irot]      = f2bf((x1 * c - x2 * sn) * FSCALE);
                    op[irot + 32] = f2bf((x1 * sn + x2 * c) * FSCALE);
                }
            }
    }
}

// ---------------------------------------------------------------------------
// kv56: kv_lat_bf @ w_kvb^T. N-regions:
//   n0 < 2048 : k_exp -> plain bf16 [4096][2048] (ldc 2048)
//   else      : v_exp -> v_exp_t [h][v][row] packed transposed bf16
// ---------------------------------------------------------------------------
__global__ __launch_bounds__(256)
void gemm_kv56(const ushort* __restrict__ A, const ushort* __restrict__ B,
               ushort* __restrict__ kexp, ushort* __restrict__ vt)
{
    __shared__ __align__(16) ushort As[128 * 32];
    __shared__ __align__(16) ushort Bs[128 * 32];
    int tid = threadIdx.x;
    int m0 = blockIdx.y * 128, n0 = blockIdx.x * 128;
    f32x4 acc[4][4] = {};
    gemm_core(A, B, As, Bs, KV_LORA, KV_LORA, KV_LORA, m0, n0, tid, acc);
    int l = tid & 63, w = tid >> 6;
    int l15 = l & 15, quad = l >> 4;
    int wm = (w >> 1) * 64, wn = (w & 1) * 64;
    if (n0 < 2048) {
        #pragma unroll
        for (int i = 0; i < 4; ++i)
            #pragma unroll
            for (int j = 0; j < 4; ++j)
                #pragma unroll
                for (int r = 0; r < 4; ++r) {
                    long gm = m0 + wm + i * 16 + quad * 4 + r;
                    kexp[gm * 2048 + n0 + wn + j * 16 + l15] = f2bf(acc[i][j][r]);
                }
    } else {
        int head = (n0 >> 7) - 16;
        #pragma unroll
        for (int i = 0; i < 4; ++i)
            #pragma unroll
            for (int j = 0; j < 4; ++j) {
                long gm0 = m0 + wm + i * 16 + quad * 4;
                int c = wn + j * 16 + l15;        // v channel
                ushort4 p;
                p.x = f2bf(acc[i][j][0]); p.y = f2bf(acc[i][j][1]);
                p.z = f2bf(acc[i][j][2]); p.w = f2bf(acc[i][j][3]);
                *(ushort4*)(vt + (long)head * 128 * 4096 + (long)c * 4096 + gm0) = p;
            }
    }
}

// G7: plain fp32-out GEMM
__global__ __launch_bounds__(256)
void gemm_f32out(const ushort* __restrict__ A, const ushort* __restrict__ B,
                 float* __restrict__ C, int K, int lda, int ldb, int ldc)
{
    __shared__ __align__(16) ushort As[128 * 32];
    __shared__ __align__(16) ushort Bs[128 * 32];
    int tid = threadIdx.x;
    int m0 = blockIdx.y * 128, n0 = blockIdx.x * 128;
    f32x4 acc[4][4] = {};
    gemm_core(A, B, As, Bs, K, lda, ldb, m0, n0, tid, acc);
    int l = tid & 63, w = tid >> 6;
    int l15 = l & 15, quad = l >> 4;
    int wm = (w >> 1) * 64, wn = (w & 1) * 64;
    #pragma unroll
    for (int i = 0; i < 4; ++i)
        #pragma unroll
        for (int j = 0; j < 4; ++j)
            #pragma unroll
            for (int r = 0; r < 4; ++r) {
                long gm = m0 + wm + i * 16 + quad * 4 + r;
                long gn = n0 + wn + j * 16 + l15;
                C[gm * ldc + gn] = acc[i][j][r];
            }
}

// ---------------------------------------------------------------------------
// Fused LayerNorm: blocks [0,4096) = qa rows, [4096,8192) = kva rows.
// ---------------------------------------------------------------------------
__global__ __launch_bounds__(256)
void ln_both(const float* __restrict__ qlat, const float* __restrict__ kvmix,
             ushort* __restrict__ qout, ushort* __restrict__ kvout,
             const float* __restrict__ gq, const float* __restrict__ bq,
             const float* __restrict__ gk, const float* __restrict__ bk)
{
    int n;
    const float* x;
    ushort* y;
    const float *g, *b;
    if (blockIdx.x < NROWS) {
        long row = blockIdx.x;
        n = Q_LORA; x = qlat + row * Q_LORA; y = qout + row * Q_LORA;
        g = gq; b = bq;
    } else {
        long row = blockIdx.x - NROWS;
        n = KV_LORA; x = kvmix + row * KV_LORA; y = kvout + row * KV_LORA;
        g = gk; b = bk;
    }
    int tid = threadIdx.x;
    float s = 0.f, ss = 0.f;
    for (int i = tid; i < n; i += 256) { float v = x[i]; s += v; ss += v * v; }
    #pragma unroll
    for (int off = 32; off > 0; off >>= 1) {
        s  += __shfl_xor(s, off);
        ss += __shfl_xor(ss, off);
    }
    __shared__ float sred[4], ssred[4];
    int wid = tid >> 6, lane = tid & 63;
    if (lane == 0) { sred[wid] = s; ssred[wid] = ss; }
    __syncthreads();
    s  = sred[0] + sred[1] + sred[2] + sred[3];
    ss = ssred[0] + ssred[1] + ssred[2] + ssred[3];
    float mu  = s / n;
    float var = ss / n - mu * mu;
    float r = 1.0f / sqrtf(var + LN_EPS);
    for (int i = tid; i < n; i += 256)
        y[i] = f2bf((x[i] - mu) * r * g[i] + b[i]);
}

// ---------------------------------------------------------------------------
// MFMA flash attention v3: 512 thr (8 waves), TQ=128, TK=64.
// Q pre-scaled by FSCALE; K staged from k_exp [4096][2048] + k_rope [4096][64].
// XOR-swizzled K/V LDS; register prefetch; ones-column row-sum.
// ---------------------------------------------------------------------------
__global__ __launch_bounds__(512, 4)
void flash_mfma(const ushort* __restrict__ qf, const ushort* __restrict__ kexp,
                const ushort* __restrict__ krope, const ushort* __restrict__ vt,
                ushort* __restrict__ attnv)
{
    __shared__ __align__(16) ushort Ks[64 * 192];    // 24.0 KB, swizzled
    __shared__ __align__(16) ushort Vs[144 * 64];    // 18.0 KB, swizzled (+ones rows)
    __shared__ __align__(16) ushort Ps[128 * 72];    // 18.0 KB, padded
    int tid = threadIdx.x;
    int w = tid >> 6, l = tid & 63, l15 = l & 15, quad = l >> 4;
    int bh = blockIdx.x;
    int b = bh >> 4, h = bh & 15;
    int q0 = blockIdx.y * 128;

    // init ones/zero rows v=128..143 (row 128 = 1.0, rest 0); swizzle-invariant
    {
        int e = 8192 + tid * 2;
        ushort2 iv;
        iv.x = (e     < 8256) ? (ushort)0x3F80 : (ushort)0;
        iv.y = (e + 1 < 8256) ? (ushort)0x3F80 : (ushort)0;
        *(ushort2*)&Vs[e] = iv;
    }

    // Q fragments: wave w owns q rows q0+16w .. q0+16w+15
    const ushort* qp = qf + ((long)(b * SS + q0 + 16 * w + l15) * NH + h) * 192 + quad * 8;
    short8 aq[6];
    #pragma unroll
    for (int kk = 0; kk < 6; ++kk) aq[kk] = *(const short8*)(qp + kk * 32);

    f32x4 o[8] = {};
    f32x4 osum = {};
    float mrow[4];
    #pragma unroll
    for (int r = 0; r < 4; ++r) mrow[r] = -INFINITY;

    // staging thread mapping
    int r0k = tid >> 3, subk = tid & 7;   // K: 64 rows x 24 chunks, 3/thread
    int v0  = tid >> 2, subv = tid & 3;   // V: 128 rows x 8 chunks, 2/thread
    const ushort* kgp0 = kexp + ((long)(b * SS) + r0k) * 2048 + h * 128;
    const ushort* kgp1 = krope + ((long)(b * SS) + r0k) * 64;
    const ushort* vgp  = vt + (long)h * 128 * 4096 + (long)b * SS + (long)v0 * 4096;

    short8 pk[3], pv[2];
    pk[0] = *(const short8*)(kgp0 + subk * 8);
    pk[1] = *(const short8*)(kgp0 + 64 + subk * 8);
    pk[2] = *(const short8*)(kgp1 + subk * 8);
    #pragma unroll
    for (int it = 0; it < 2; ++it)
        pv[it] = *(const short8*)(vgp + (subv + 4 * it) * 8);

    int ksw = r0k & 7, vsw = v0 & 7;

    for (int k0 = 0; k0 < SS; k0 += 64) {
        __syncthreads();   // prior compute done reading Ks/Vs
        #pragma unroll
        for (int it = 0; it < 3; ++it)
            *(short8*)&Ks[r0k * 192 + ((subk + 8 * it) ^ ksw) * 8] = pk[it];
        #pragma unroll
        for (int it = 0; it < 2; ++it)
            *(short8*)&Vs[v0 * 64 + ((subv + 4 * it) ^ vsw) * 8] = pv[it];
        __syncthreads();
        if (k0 + 64 < SS) {   // prefetch next tile (loads in flight during compute)
            const ushort* kg0 = kgp0 + (long)(k0 + 64) * 2048;
            const ushort* kg1 = kgp1 + (long)(k0 + 64) * 64;
            const ushort* vg  = vgp + (k0 + 64);
            pk[0] = *(const short8*)(kg0 + subk * 8);
            pk[1] = *(const short8*)(kg0 + 64 + subk * 8);
            pk[2] = *(const short8*)(kg1 + subk * 8);
            #pragma unroll
            for (int it = 0; it < 2; ++it)
                pv[it] = *(const short8*)(vg + (subv + 4 * it) * 8);
        }

        // QK^T: C[q=quad*4+r][kcol=j*16+l15]  (scores pre-scaled via Q)
        f32x4 sc[4] = {};
        #pragma unroll
        for (int kk = 0; kk < 6; ++kk) {
            #pragma unroll
            for (int j = 0; j < 4; ++j) {
                int krow = j * 16 + l15;
                short8 bfr = *(const short8*)&Ks[krow * 192 + (((kk * 4 + quad) ^ (krow & 7))) * 8];
                sc[j] = __builtin_amdgcn_mfma_f32_16x16x32_bf16(aq[kk], bfr, sc[j], 0, 0, 0);
            }
        }

        // online softmax (max via shuffles; sum via ones-column MFMA)
        #pragma unroll
        for (int r = 0; r < 4; ++r) {
            float s0 = sc[0][r], s1 = sc[1][r];
            float s2 = sc[2][r], s3 = sc[3][r];
            float mx = fmaxf(fmaxf(s0, s1), fmaxf(s2, s3));
            mx = fmaxf(mx, __shfl_xor(mx, 1));
            mx = fmaxf(mx, __shfl_xor(mx, 2));
            mx = fmaxf(mx, __shfl_xor(mx, 4));
            mx = fmaxf(mx, __shfl_xor(mx, 8));
            float mnew = fmaxf(mrow[r], mx);
            float alpha = __expf(mrow[r] - mnew);
            mrow[r] = mnew;
            float p0 = __expf(s0 - mnew), p1 = __expf(s1 - mnew);
            float p2 = __expf(s2 - mnew), p3 = __expf(s3 - mnew);
            #pragma unroll
            for (int v8 = 0; v8 < 8; ++v8) o[v8][r] *= alpha;
            osum[r] *= alpha;
            int prow = (16 * w + quad * 4 + r) * 72;
            Ps[prow + l15]      = f2bf(p0);
            Ps[prow + 16 + l15] = f2bf(p1);
            Ps[prow + 32 + l15] = f2bf(p2);
            Ps[prow + 48 + l15] = f2bf(p3);
        }

        // PV + row-sum (same-wave Ps, no barrier needed)
        #pragma unroll
        for (int ks = 0; ks < 2; ++ks) {
            short8 pa = *(const short8*)&Ps[(16 * w + l15) * 72 + ks * 32 + quad * 8];
            #pragma unroll
            for (int v8 = 0; v8 < 8; ++v8) {
                int vrow = v8 * 16 + l15;
                short8 bv = *(const short8*)&Vs[vrow * 64 + (((ks * 4 + quad) ^ (vrow & 7))) * 8];
                o[v8] = __builtin_amdgcn_mfma_f32_16x16x32_bf16(pa, bv, o[v8], 0, 0, 0);
            }
            {
                int vrow = 128 + l15;
                short8 bv = *(const short8*)&Vs[vrow * 64 + (((ks * 4 + quad) ^ (vrow & 7))) * 8];
                osum = __builtin_amdgcn_mfma_f32_16x16x32_bf16(pa, bv, osum, 0, 0, 0);
            }
        }
    }

    #pragma unroll
    for (int r = 0; r < 4; ++r) {
        float lsum = __shfl(osum[r], l & 48);   // broadcast from l15==0 of this quad
        float inv = 1.0f / lsum;
        long rowi = (long)(b * SS) + q0 + 16 * w + quad * 4 + r;
        ushort* op = attnv + (rowi * NH + h) * 128;
        #pragma unroll
        for (int v8 = 0; v8 < 8; ++v8)
            op[v8 * 16 + l15] = f2bf(o[v8][r] * inv);
    }
}

// ---------------------------------------------------------------------------

extern "C" void kernel_launch(void* const* d_in, const int* in_sizes, int n_in,
                              void* d_out, int out_size, void* d_ws, size_t ws_size,
                              hipStream_t stream) {
    const float* hs       = (const float*)d_in[0];
    const float* w_qa     = (const float*)d_in[1];
    const float* ln_qa_g  = (const float*)d_in[2];
    const float* ln_qa_b  = (const float*)d_in[3];
    const float* w_qb     = (const float*)d_in[4];
    const float* w_qrope  = (const float*)d_in[5];
    const float* w_kva    = (const float*)d_in[6];
    const float* ln_kva_g = (const float*)d_in[7];
    const float* ln_kva_b = (const float*)d_in[8];
    const float* w_kvb    = (const float*)d_in[9];
    const float* w_o      = (const float*)d_in[10];
    const int*   pos      = (const int*)d_in[11];
    float* out = (float*)d_out;

    char* W = (char*)d_ws;
    ushort* w_qa_bf    = (ushort*)(W + 0);           //  6,291,456
    ushort* w_kva_bf   = (ushort*)(W + 6291456);     //  2,621,440 (adjacent to w_qa!)
    ushort* hs_bf      = (ushort*)(W + 8912896);     // 16,777,216
    ushort* w_qb_bf    = (ushort*)(W + 25690112);    //  6,291,456
    ushort* w_qrope_bf = (ushort*)(W + 31981568);    //  3,145,728 (adjacent to w_qb!)
    ushort* w_kvb_bf   = (ushort*)(W + 35127296);    //  4,194,304
    ushort* w_o_bf     = (ushort*)(W + 39321600);    //  8,388,608
    float*  cosT       = (float*)(W + 47710208);     //    262,144
    float*  sinT       = (float*)(W + 47972352);     //    262,144
    float*  q_lat_f    = (float*)(W + 48234496);     // 25,165,824
    float*  kv_mix     = (float*)(W + 73400320);     //  8,388,608
    ushort* k_rope     = (ushort*)(W + 81788928);    //    524,288
    ushort* q_lat_bf   = (ushort*)(W + 82313216);    // 12,582,912
    ushort* kv_lat_bf  = (ushort*)(W + 94896128);    //  4,194,304
    ushort* q_full     = (ushort*)(W + 99090432);    // 25,165,824
    ushort* k_exp      = (ushort*)(W + 124256256);   // 16,777,216
    ushort* v_exp_t    = (ushort*)(W + 141033472);   // 16,777,216
    ushort* attnv_bf   = (ushort*)(W + 157810688);   // 16,777,216 (end 174,587,904)

    dim3 blk(256);

    // 1. trig table
    build_trig<<<dim3(256), blk, 0, stream>>>(pos, cosT, sinT);
    // 2. all converts
    cvt_all<<<dim3(23296), blk, 0, stream>>>(
        hs, w_qa, w_qb, w_qrope, w_kvb, w_o, w_kva,
        hs_bf, w_qa_bf, w_qb_bf, w_qrope_bf, w_kvb_bf, w_o_bf, w_kva_bf);
    // 3. mega1: q_mixed + kv_mix + rope'd k_rope
    gemm_mega1<<<dim3(17, 32), blk, 0, stream>>>(
        hs_bf, w_qa_bf, q_lat_f, kv_mix, k_rope, cosT, sinT);
    // 4. both LNs
    ln_both<<<dim3(2 * NROWS), blk, 0, stream>>>(
        q_lat_f, kv_mix, q_lat_bf, kv_lat_bf, ln_qa_g, ln_qa_b, ln_kva_g, ln_kva_b);
    // 5. q_nope + rope'd q_rope (both x FSCALE) -> q_full
    gemm_q23<<<dim3(24, 32), blk, 0, stream>>>(
        q_lat_bf, w_qb_bf, q_full, cosT, sinT);
    // 6. k_exp + v_exp_t
    gemm_kv56<<<dim3(32, 32), blk, 0, stream>>>(
        kv_lat_bf, w_kvb_bf, k_exp, v_exp_t);
    // 7. flash attention (XCD-affine grid: x=bh, y=q-block)
    flash_mfma<<<dim3(BB * NH, SS / 128), dim3(512), 0, stream>>>(
        q_full, k_exp, k_rope, v_exp_t, attnv_bf);
    // 8. out = attnv @ w_o^T -> fp32
    gemm_f32out<<<dim3(16, 32), blk, 0, stream>>>(
        attnv_bf, w_o_bf, out, NH * DV, NH * DV, NH * DV, D_MODEL);
}